// Round 1
// 466.612 us; speedup vs baseline: 1.2458x; 1.2458x over previous
//
#include <hip/hip_runtime.h>
#include <math.h>

#define ETA 0.1f

#define C0 1.0f
#define C1 1.0f
#define C2 0.5f
#define C3 (1.0f/6.0f)
#define C4 (1.0f/24.0f)
#define C5 (1.0f/120.0f)
#define C6 (1.0f/720.0f)
#define C7 (1.0f/5040.0f)
#define C8 (1.0f/40320.0f)
#define C9 (1.0f/362880.0f)

typedef __attribute__((ext_vector_type(8))) short short8;
typedef __attribute__((ext_vector_type(4))) float f32x4;

// fp32 staging buffer swizzle (16 float4-chunks per row, XOR by row)
__device__ __forceinline__ int swzF(int r, int cc) { return r * 64 + 4 * (cc ^ (r & 15)); }

// bf16 row-major layout (ushort units)
__device__ __forceinline__ int rmI(int r, int c) {
    return r * 64 + 8 * ((c >> 3) ^ (r & 7)) + (c & 7);
}
// bf16 col-major layout
__device__ __forceinline__ int cmI(int r, int c) {
    return c * 64 + 8 * ((r >> 3) ^ (c & 7)) + (r & 7);
}

// split fp32 -> bf16 hi (RNE) + bf16 lo (trunc of residual)
__device__ __forceinline__ void splitbf(float x, unsigned short& h, unsigned short& l) {
    unsigned u = __float_as_uint(x);
    unsigned r = u + 0x7FFFu + ((u >> 16) & 1u);
    h = (unsigned short)(r >> 16);
    float d = x - __uint_as_float(r & 0xFFFF0000u);
    l = (unsigned short)(__float_as_uint(d) >> 16);
}
__device__ __forceinline__ float bf2f(unsigned short h) {
    return __uint_as_float(((unsigned)h) << 16);
}

// One 64x64 matmul stage on MFMA, split-bf16 4 products. Fully in-place safe:
// ALL LDS reads (A-frags, B-frags) complete before the mid-barrier; writes follow.
// cm-out value: cmIsT0 ? (cB*bm + cI*I)           [T0 built from reg-resident Bm]
//                      : (acc + cB*bm + cI*I)
// rm-out value (if ORh): acc (incl. cB/cI adds when !cmIsT0 -> X0; raw B2 when cmIsT0)
__device__ __forceinline__ void mmstage(
    const unsigned short* Ah, const unsigned short* Al,
    const unsigned short* Bh, const unsigned short* Bl,
    unsigned short* Oh, unsigned short* Ol,
    unsigned short* ORh, unsigned short* ORl,
    const float* bmf, float cI, float cB, bool cmIsT0,
    int wv, int lane)
{
    const int n16 = lane & 15;
    const int q = lane >> 4;           // 0..3
    const int mrow = 16 * wv + n16;    // A-operand row for this lane

    short8 ah[2], al[2], bh[4][2], bl[4][2];
#pragma unroll
    for (int ks = 0; ks < 2; ++ks) {
        int k0 = 32 * ks + 8 * q;
        int ia = rmI(mrow, k0);
        ah[ks] = *(const short8*)(Ah + ia);
        al[ks] = *(const short8*)(Al + ia);
#pragma unroll
        for (int t4 = 0; t4 < 4; ++t4) {
            int ib = cmI(k0, 16 * t4 + n16);
            bh[t4][ks] = *(const short8*)(Bh + ib);
            bl[t4][ks] = *(const short8*)(Bl + ib);
        }
    }

    f32x4 acc[4] = {{0.f,0.f,0.f,0.f},{0.f,0.f,0.f,0.f},{0.f,0.f,0.f,0.f},{0.f,0.f,0.f,0.f}};
#pragma unroll
    for (int ks = 0; ks < 2; ++ks) {
#pragma unroll
        for (int t4 = 0; t4 < 4; ++t4)
            acc[t4] = __builtin_amdgcn_mfma_f32_16x16x32_bf16(ah[ks], bh[t4][ks], acc[t4], 0, 0, 0);
#pragma unroll
        for (int t4 = 0; t4 < 4; ++t4)
            acc[t4] = __builtin_amdgcn_mfma_f32_16x16x32_bf16(al[ks], bl[t4][ks], acc[t4], 0, 0, 0);
#pragma unroll
        for (int t4 = 0; t4 < 4; ++t4)
            acc[t4] = __builtin_amdgcn_mfma_f32_16x16x32_bf16(ah[ks], bl[t4][ks], acc[t4], 0, 0, 0);
#pragma unroll
        for (int t4 = 0; t4 < 4; ++t4)
            acc[t4] = __builtin_amdgcn_mfma_f32_16x16x32_bf16(al[ks], bh[t4][ks], acc[t4], 0, 0, 0);
    }

    const int rbase = 16 * wv + 4 * q;   // C/D: row = 16*wv + 4*q + reg, col = 16*t4 + n16
    float cmv[4][4];
#pragma unroll
    for (int t4 = 0; t4 < 4; ++t4) {
        int c = 16 * t4 + n16;
#pragma unroll
        for (int rg = 0; rg < 4; ++rg) {
            float a = acc[t4][rg];
            if (bmf) {
                float add = cB * bmf[4 * t4 + rg] + ((rbase + rg) == c ? cI : 0.f);
                if (cmIsT0) { cmv[t4][rg] = add; }            // T0; rm keeps raw B2
                else        { a += add; cmv[t4][rg] = a; acc[t4][rg] = a; }
            } else {
                cmv[t4][rg] = a;
            }
        }
    }

    __syncthreads();   // all reads done before any write (in-place aliasing)

#pragma unroll
    for (int t4 = 0; t4 < 4; ++t4) {
        int c = 16 * t4 + n16;
        {
            unsigned short h[4], l[4];
#pragma unroll
            for (int rg = 0; rg < 4; ++rg) splitbf(cmv[t4][rg], h[rg], l[rg]);
            int io = cmI(rbase, c);   // 4 consecutive rows, same half-chunk -> b64
            *(ushort4*)(Oh + io) = make_ushort4(h[0], h[1], h[2], h[3]);
            *(ushort4*)(Ol + io) = make_ushort4(l[0], l[1], l[2], l[3]);
        }
        if (ORh) {
            unsigned short h[4], l[4];
#pragma unroll
            for (int rg = 0; rg < 4; ++rg) splitbf(acc[t4][rg], h[rg], l[rg]);
#pragma unroll
            for (int rg = 0; rg < 4; ++rg) {
                int io = rmI(rbase + rg, c);
                ORh[io] = h[rg];
                ORl[io] = l[rg];
            }
        }
    }
    __syncthreads();
}

__global__ __launch_bounds__(256, 4) void meg_expm_kernel(
    const float* __restrict__ Rg, const float* __restrict__ Gg,
    float* __restrict__ out)
{
    // 32 KiB LDS, carved into two h/l pairs. Everything runs in-place:
    //   rm pair: Bm -> B2 -> X0 -> X^2 ...   (A-operand, row-major)
    //   cm pair: G-f32 / A-f32 -> Bm -> T0 -> T ... -> X0 -> X^2 ... (B-operand, col-major)
    // Bm itself is register-resident per lane (16 C/D-fragment values) for the
    // Horner +cB*Bm adds, so no third buffer pair is needed.
    __shared__ __align__(16) unsigned short sm[16384];
    unsigned short* rmh = sm;              // row-major h
    unsigned short* rml = sm + 4096;       // row-major l
    unsigned short* cmh = sm + 8192;       // col-major h
    unsigned short* cml = sm + 12288;      // col-major l
    float* FBG = (float*)sm;               // fp32 G staging (over rm pair)
    float* FBA = (float*)(sm + 8192);      // fp32 A (over cm pair)
    float* wmax = (float*)sm;              // 4 per-wave norm maxima (over rm pair; G dead)

    const int t = threadIdx.x;
    const int wv = t >> 6, lane = t & 63;
    const int tx = t & 15, ty = t >> 4;
    const long long base = (long long)blockIdx.x * 4096;

    // ---- stage grad into FBG (coalesced float4) ----
#pragma unroll
    for (int i = 0; i < 4; ++i) {
        int idx = t + i * 256;
        int r = idx >> 4, cc = idx & 15;
        *(float4*)&FBG[swzF(r, cc)] = ((const float4*)(Gg + base))[idx];
    }
    __syncthreads();

    // ---- A = log(R) - ETA*(G - G^T) -> FBA (fp32, swizzled) ----
#pragma unroll
    for (int i = 0; i < 4; ++i) {
        int r = 4 * ty + i;
        float4 rv = *(const float4*)&Rg[base + r * 64 + 4 * tx];
        float4 gv = *(const float4*)&FBG[swzF(r, tx)];
        float gt[4];
#pragma unroll
        for (int j = 0; j < 4; ++j)
            gt[j] = FBG[swzF(4 * tx + j, r >> 2) + (r & 3)];   // G[c][r]
        float4 o;
        o.x = logf(rv.x) - ETA * (gv.x - gt[0]);
        o.y = logf(rv.y) - ETA * (gv.y - gt[1]);
        o.z = logf(rv.z) - ETA * (gv.z - gt[2]);
        o.w = logf(rv.w) - ETA * (gv.w - gt[3]);
        *(float4*)&FBA[swzF(r, tx)] = o;
    }
    __syncthreads();

    // ---- 1-norm: each wave sums 16 cols (4 lanes/col, 16 rows each) ----
    {
        int c = 16 * wv + (lane & 15);
        int rq = lane >> 4;
        float cs = 0.f;
#pragma unroll
        for (int rr = 0; rr < 16; ++rr) {
            int r = 16 * rq + rr;
            cs += fabsf(FBA[swzF(r, c >> 2) + (c & 3)]);
        }
        cs += __shfl_xor(cs, 16);
        cs += __shfl_xor(cs, 32);
        cs = fmaxf(cs, __shfl_xor(cs, 8));
        cs = fmaxf(cs, __shfl_xor(cs, 4));
        cs = fmaxf(cs, __shfl_xor(cs, 2));
        cs = fmaxf(cs, __shfl_xor(cs, 1));
        if (lane == 0) wmax[wv] = cs;
    }
    __syncthreads();

    const float nrm = fmaxf(fmaxf(wmax[0], wmax[1]), fmaxf(wmax[2], wmax[3]));
    int s = 0;
    if (nrm > 1.0f) {
        s = (int)ceilf(log2f(nrm));
        if (s > 30) s = 30;
        if (s < 0) s = 0;
    }
    const float scale = exp2f(-(float)s);

    // ---- read A back, scale, split into Bm h/l (staging-position 4x4 block) ----
    unsigned short abmh[4][4], abml[4][4];
#pragma unroll
    for (int i = 0; i < 4; ++i) {
        int r = 4 * ty + i;
        float4 a = *(const float4*)&FBA[swzF(r, tx)];
        float av[4] = { a.x, a.y, a.z, a.w };
#pragma unroll
        for (int j = 0; j < 4; ++j)
            splitbf(av[j] * scale, abmh[i][j], abml[i][j]);
    }
    __syncthreads();   // FBA/wmax reads done before overwrites below

    // ---- write Bm row-major (rm pair) and col-major (cm pair, over dead A-f32) ----
#pragma unroll
    for (int i = 0; i < 4; ++i) {
        int r = 4 * ty + i;
        *(ushort4*)(rmh + rmI(r, 4 * tx)) = make_ushort4(abmh[i][0], abmh[i][1], abmh[i][2], abmh[i][3]);
        *(ushort4*)(rml + rmI(r, 4 * tx)) = make_ushort4(abml[i][0], abml[i][1], abml[i][2], abml[i][3]);
#pragma unroll
        for (int j = 0; j < 4; ++j) {
            int ic = cmI(r, 4 * tx + j);
            cmh[ic] = abmh[i][j];
            cml[ic] = abml[i][j];
        }
    }
    __syncthreads();

    // ---- gather Bm at this lane's C/D fragment positions into 16 regs ----
    // (reads only; stays in the same read-epoch as M1's fragment loads)
    const int n16 = lane & 15, q = lane >> 4;
    const int rbase = 16 * wv + 4 * q;
    float bmf[16];
#pragma unroll
    for (int t4 = 0; t4 < 4; ++t4) {
        int ib = cmI(rbase, 16 * t4 + n16);
        ushort4 hh = *(const ushort4*)(cmh + ib);
        ushort4 ll = *(const ushort4*)(cml + ib);
        bmf[4 * t4 + 0] = bf2f(hh.x) + bf2f(ll.x);
        bmf[4 * t4 + 1] = bf2f(hh.y) + bf2f(ll.y);
        bmf[4 * t4 + 2] = bf2f(hh.z) + bf2f(ll.z);
        bmf[4 * t4 + 3] = bf2f(hh.w) + bf2f(ll.w);
    }

    // ---- M1: B2 = Bm*Bm -> rm (in-place); T0 = C9*Bm + C8*I -> cm (from regs) ----
    mmstage(rmh, rml, cmh, cml, cmh, cml, rmh, rml, bmf, C8, C9, true,  wv, lane);

    // ---- Horner (B2 and T commute): T' = B2*T + cI*I + cB*Bm, cm in-place ----
    mmstage(rmh, rml, cmh, cml, cmh, cml, nullptr, nullptr, bmf, C6, C7, false, wv, lane);
    mmstage(rmh, rml, cmh, cml, cmh, cml, nullptr, nullptr, bmf, C4, C5, false, wv, lane);
    mmstage(rmh, rml, cmh, cml, cmh, cml, nullptr, nullptr, bmf, C2, C3, false, wv, lane);
    // last Horner: X0 -> cm and rm (rm overwrites B2; mid-barrier guards)
    mmstage(rmh, rml, cmh, cml, cmh, cml, rmh, rml, bmf, C0, C1, false, wv, lane);

    // ---- s squarings: X <- X*X, fully in-place on rm+cm ----
    for (int it = 0; it < s; ++it) {
        bool lastp = (it == s - 1);
        mmstage(rmh, rml, cmh, cml, cmh, cml,
                lastp ? nullptr : rmh, lastp ? nullptr : rml,
                nullptr, 0.f, 0.f, false, wv, lane);
    }

    // ---- readout: fp32 = h + l from col-major, coalesced float4 stores ----
#pragma unroll
    for (int i = 0; i < 4; ++i) {
        int g = i * 256 + t;
        int r = g >> 4, cg = g & 15;
        float ov[4];
#pragma unroll
        for (int j = 0; j < 4; ++j) {
            int c = 4 * cg + j;
            int ic = cmI(r, c);
            ov[j] = bf2f(cmh[ic]) + bf2f(cml[ic]);
        }
        float4 o;
        o.x = ov[0]; o.y = ov[1]; o.z = ov[2]; o.w = ov[3];
        ((float4*)(out + base))[g] = o;
    }
}

extern "C" void kernel_launch(void* const* d_in, const int* in_sizes, int n_in,
                              void* d_out, int out_size, void* d_ws, size_t ws_size,
                              hipStream_t stream) {
    const float* R = (const float*)d_in[0];
    const float* G = (const float*)d_in[1];
    float* o = (float*)d_out;
    const int B = in_sizes[0] / (64 * 64);
    meg_expm_kernel<<<dim3(B), dim3(256), 0, stream>>>(R, G, o);
}